// Round 3
// baseline (557.530 us; speedup 1.0000x reference)
//
#include <hip/hip_runtime.h>
#include <hip/hip_bf16.h>

typedef __attribute__((ext_vector_type(8))) short short8;
typedef __attribute__((ext_vector_type(4))) float f32x4;

#define DI __device__ __forceinline__

// f32 -> bf16 round-to-nearest-even (bit twiddle; inputs are never NaN)
DI unsigned short f2b(float x) {
    unsigned int u = __builtin_bit_cast(unsigned int, x);
    u += 0x7FFFu + ((u >> 16) & 1u);
    return (unsigned short)(u >> 16);
}

DI void gload_lds16(const void* g, void* l) {
    __builtin_amdgcn_global_load_lds(
        (const __attribute__((address_space(1))) void*)g,
        (__attribute__((address_space(3))) void*)l, 16, 0, 0);
}

// ---------------- f32 -> bf16 bulk convert (vectorized, G13) ----------------
__global__ __launch_bounds__(256) void cvt_bf16(const float* __restrict__ src,
                                                unsigned short* __restrict__ dst, int n8) {
    int i = blockIdx.x * blockDim.x + threadIdx.x;
    if (i >= n8) return;
    const float4* s = (const float4*)src + 2 * (size_t)i;
    float4 a = s[0], b = s[1];
    short8 o;
    o[0] = (short)f2b(a.x); o[1] = (short)f2b(a.y); o[2] = (short)f2b(a.z); o[3] = (short)f2b(a.w);
    o[4] = (short)f2b(b.x); o[5] = (short)f2b(b.y); o[6] = (short)f2b(b.z); o[7] = (short)f2b(b.w);
    *(short8*)(dst + 8 * (size_t)i) = o;
}

// -------- RoPE cos/sin table: [4096 pos][32 freq] float2, f64-accurate -------
__global__ __launch_bounds__(256) void trig_tab(float2* __restrict__ cs) {
    int idx = blockIdx.x * blockDim.x + threadIdx.x;
    if (idx >= 4096 * 32) return;
    int pos = idx >> 5, i = idx & 31;
    double inv = exp(-(double)i * (9.210340371976184 / 32.0)); // 10000^(-i/32)
    double a = (double)pos * inv;
    cs[idx] = make_float2((float)cos(a), (float)sin(a));
}

// ---------------- 128x128 bf16 GEMM (m97 structure), B^T layout -------------
// EPI==0: C (f32, width 2048) = A @ Bw^T              -> final output
// EPI==1: fused QKV + RoPE epilogue -> q_bf/k_bf/v_bf (bf16)
template <int EPI>
__global__ __launch_bounds__(256) void gemm128(const unsigned short* __restrict__ A,
                                               const unsigned short* __restrict__ Bw,
                                               float* __restrict__ Cout,
                                               unsigned short* __restrict__ q_bf,
                                               unsigned short* __restrict__ k_bf,
                                               unsigned short* __restrict__ v_bf,
                                               const float2* __restrict__ cs) {
    constexpr int K = 2048;
    __shared__ unsigned short At[128 * 32];
    __shared__ unsigned short Bt[128 * 32];
    const int tid = threadIdx.x;
    const int lane = tid & 63, w = tid >> 6;
    const int wm = w >> 1, wn = w & 1;
    const int bm = blockIdx.x, bn = blockIdx.y;
    const int r16 = lane & 15, hi = lane >> 4;
    const int rowc = tid >> 2, slotc = tid & 3;

    f32x4 acc[4][4] = {};

    for (int kt = 0; kt < K / 32; ++kt) {
        __syncthreads();
#pragma unroll
        for (int p = 0; p < 2; ++p) {
            int row = p * 64 + rowc;
            gload_lds16(A + (long)(bm * 128 + row) * K + kt * 32 + slotc * 8,
                        (char*)At + p * 4096 + w * 1024);
            gload_lds16(Bw + (long)(bn * 128 + row) * K + kt * 32 + slotc * 8,
                        (char*)Bt + p * 4096 + w * 1024);
        }
        asm volatile("s_waitcnt vmcnt(0)" ::: "memory");
        __syncthreads();
        short8 af[4], bfr[4];
#pragma unroll
        for (int mf = 0; mf < 4; ++mf)
            af[mf] = *(const short8*)(At + (wm * 64 + mf * 16 + r16) * 32 + hi * 8);
#pragma unroll
        for (int nf = 0; nf < 4; ++nf)
            bfr[nf] = *(const short8*)(Bt + (wn * 64 + nf * 16 + r16) * 32 + hi * 8);
#pragma unroll
        for (int mf = 0; mf < 4; ++mf)
#pragma unroll
            for (int nf = 0; nf < 4; ++nf)
                acc[mf][nf] = __builtin_amdgcn_mfma_f32_16x16x32_bf16(af[mf], bfr[nf], acc[mf][nf], 0, 0, 0);
    }

    if (EPI == 0) {
#pragma unroll
        for (int mf = 0; mf < 4; ++mf)
#pragma unroll
            for (int r = 0; r < 4; ++r) {
                long row = (long)bm * 128 + wm * 64 + mf * 16 + hi * 4 + r;
                float* o = Cout + row * 2048 + bn * 128 + wn * 64 + r16;
                o[0] = acc[mf][0][r]; o[16] = acc[mf][1][r]; o[32] = acc[mf][2][r]; o[48] = acc[mf][3][r];
            }
    } else {
        const int colBase = bn * 128 + wn * 64;  // 64-wide span == one head exactly
        const int b = bm >> 5;
        unsigned short* dst;
        bool dorope;
        if (colBase < 2048)      { dst = q_bf + (long)(b * 32 + (colBase >> 6)) * 4096 * 64; dorope = true; }
        else if (colBase < 2560) { dst = k_bf + (long)(b * 8 + ((colBase - 2048) >> 6)) * 4096 * 64; dorope = true; }
        else                     { dst = v_bf + (long)(b * 8 + ((colBase - 2560) >> 6)) * 4096 * 64; dorope = false; }
#pragma unroll
        for (int mf = 0; mf < 4; ++mf)
#pragma unroll
            for (int r = 0; r < 4; ++r) {
                int pos = (bm * 128 + wm * 64 + mf * 16 + hi * 4 + r) & 4095;
                if (dorope) {
#pragma unroll
                    for (int nf = 0; nf < 2; ++nf) {
                        int i = nf * 16 + r16;
                        float2 c2 = cs[pos * 32 + i];
                        float x1 = acc[mf][nf][r], x2 = acc[mf][nf + 2][r];
                        dst[(long)pos * 64 + i]      = f2b(x1 * c2.x - x2 * c2.y);
                        dst[(long)pos * 64 + 32 + i] = f2b(x2 * c2.x + x1 * c2.y);
                    }
                } else {
#pragma unroll
                    for (int nf = 0; nf < 4; ++nf)
                        dst[(long)pos * 64 + nf * 16 + r16] = f2b(acc[mf][nf][r]);
                }
            }
    }
}

// ---------------- V transpose: [plane][pos][d] -> [plane][d][pos] ----------------
__global__ __launch_bounds__(256) void transpose_v(const unsigned short* __restrict__ v,
                                                   unsigned short* __restrict__ vT) {
    __shared__ unsigned short t[64][65];
    const int plane = blockIdx.y;
    const int p0 = blockIdx.x * 64;
    const int tid = threadIdx.x;
    const int rr = tid >> 2, c0 = (tid & 3) * 16;
    const unsigned short* src = v + (long)plane * 4096 * 64 + (long)(p0 + rr) * 64 + c0;
    short8 x0 = *(const short8*)src, x1 = *(const short8*)(src + 8);
#pragma unroll
    for (int j = 0; j < 8; ++j) t[rr][c0 + j] = (unsigned short)x0[j];
#pragma unroll
    for (int j = 0; j < 8; ++j) t[rr][c0 + 8 + j] = (unsigned short)x1[j];
    __syncthreads();
    short8 o0, o1;
#pragma unroll
    for (int j = 0; j < 8; ++j) o0[j] = (short)t[c0 + j][rr];
#pragma unroll
    for (int j = 0; j < 8; ++j) o1[j] = (short)t[c0 + 8 + j][rr];
    unsigned short* d = vT + (long)plane * 64 * 4096 + (long)rr * 4096 + p0 + c0;
    *(short8*)d = o0;
    *(short8*)(d + 8) = o1;
}

// ---------------- sliding-window attention ----------------
// grid (NB=8, H=32, B=2), 512 threads (8 waves). Wave w owns q-rows {w*16 + mf*128}.
// No online softmax: logits are bounded (|s| <~ 7) -> accumulate exp(s) directly,
// normalize at the end by sum + exp(tau).  K LDS [kk][d], V LDS [d][kk], both
// XOR-swizzled via pre-swizzled global source (global_load_lds is linear-dest).
// T5 setprio wraps MFMA clusters: waves here have divergent per-fragment validity
// (striped q-rows) -> role diversity -> the attn-favorable regime (m191).
__global__ __launch_bounds__(512, 2) void attn_kernel(const unsigned short* __restrict__ q_bf,
                                                      const unsigned short* __restrict__ k_bf,
                                                      const unsigned short* __restrict__ v_bfT,
                                                      const float* __restrict__ bias,
                                                      const float* __restrict__ tau,
                                                      unsigned short* __restrict__ o_bf) {
    __shared__ unsigned short Kt[64 * 64];
    __shared__ unsigned short Vt[64 * 64];
    __shared__ unsigned short Pl[8][640];  // per-wave [16 q][40] (pad keeps 16B align, banks ok)
    __shared__ float bias_l[512];

    const int nb = blockIdx.x, h = blockIdx.y, b = blockIdx.z;
    const int kvh = h >> 2;
    const int tid = threadIdx.x;
    const int lane = tid & 63, w = tid >> 6;
    const int r16 = lane & 15, hi = lane >> 4;

    bias_l[tid] = bias[h * 512 + tid];
    const float tauh = tau[h];

    const unsigned short* qp = q_bf + ((long)(b * 32 + h) * 4096 + nb * 512) * 64;
    const unsigned short* kp = k_bf + (long)(b * 8 + kvh) * 4096 * 64;
    const unsigned short* vp = v_bfT + (long)(b * 8 + kvh) * 64 * 4096;
    const int k0 = nb * 512 - 512;

    short8 aq[4][2];
#pragma unroll
    for (int mf = 0; mf < 4; ++mf) {
        int mq = w * 16 + mf * 128;
#pragma unroll
        for (int dk = 0; dk < 2; ++dk)
            aq[mf][dk] = *(const short8*)(qp + (long)(mq + r16) * 64 + dk * 32 + hi * 8);
    }

    f32x4 oacc[4][4] = {};
    float psum[4][4] = {};

    const int srow = tid >> 3, sslot = tid & 7;
    const int swz = sslot ^ (srow & 7);
    unsigned short* plw = Pl[w];

    for (int t = 0; t < 16; ++t) {
        if (nb == 0 && t < 8) continue;  // whole tile masked; uniform across block
        __syncthreads();
        {
            int jr = k0 + t * 64 + srow; if (jr < 0) jr = 0;
            gload_lds16(kp + (long)jr * 64 + swz * 8, (char*)Kt + w * 1024);
            int jc = k0 + t * 64 + swz * 8; if (jc < 0) jc = 0;
            gload_lds16(vp + (long)srow * 4096 + jc, (char*)Vt + w * 1024);
        }
        asm volatile("s_waitcnt vmcnt(0)" ::: "memory");
        __syncthreads();

        short8 bk[4][2], vb[4][2];
#pragma unroll
        for (int nf = 0; nf < 4; ++nf) {
            int rowK = nf * 16 + r16;
            int xo = (rowK & 7) << 4;
#pragma unroll
            for (int ks = 0; ks < 2; ++ks) {
                bk[nf][ks] = *(const short8*)((const char*)Kt + rowK * 128 + ((hi * 16 + ks * 64) ^ xo));
                vb[nf][ks] = *(const short8*)((const char*)Vt + rowK * 128 + ((hi * 16 + ks * 64) ^ xo));
            }
        }

#pragma unroll
        for (int mf = 0; mf < 4; ++mf) {
            const int mq = w * 16 + mf * 128;
            bool valid = (t * 64 + 63 > mq) && (t * 64 <= mq + 527);
            if (!valid) continue;
#pragma unroll
            for (int half = 0; half < 2; ++half) {
#pragma unroll
                for (int nn = 0; nn < 2; ++nn) {
                    const int nfs = half * 2 + nn;
                    f32x4 s = {};
                    __builtin_amdgcn_s_setprio(1);
                    s = __builtin_amdgcn_mfma_f32_16x16x32_bf16(aq[mf][0], bk[nfs][0], s, 0, 0, 0);
                    s = __builtin_amdgcn_mfma_f32_16x16x32_bf16(aq[mf][1], bk[nfs][1], s, 0, 0, 0);
                    __builtin_amdgcn_s_setprio(0);
                    const int kkl = t * 64 + nfs * 16 + r16;
#pragma unroll
                    for (int r = 0; r < 4; ++r) {
                        const int q = mq + hi * 4 + r;
                        const int rel = q - kkl + 512;
                        bool ok = (rel >= 0) && (rel < 512) && (nb > 0 || kkl >= 512);
                        int relc = rel < 0 ? 0 : (rel > 511 ? 511 : rel);
                        float sv = ok ? (s[r] * 0.125f + bias_l[relc]) : -1e30f;
                        float pv = __expf(sv);
                        psum[mf][r] += pv;
                        plw[(hi * 4 + r) * 40 + nn * 16 + r16] = f2b(pv);
                    }
                }
                short8 pa;
                __builtin_memcpy(&pa, plw + r16 * 40 + hi * 8, 16);  // ordered vs the u16 stores
                __builtin_amdgcn_s_setprio(1);
#pragma unroll
                for (int nfd = 0; nfd < 4; ++nfd)
                    oacc[mf][nfd] = __builtin_amdgcn_mfma_f32_16x16x32_bf16(pa, vb[nfd][half], oacc[mf][nfd], 0, 0, 0);
                __builtin_amdgcn_s_setprio(0);
            }
        }
    }

    // row-sum lives distributed over the 16 lanes sharing `hi`: butterfly over bits 0-3
#pragma unroll
    for (int mf = 0; mf < 4; ++mf)
#pragma unroll
        for (int r = 0; r < 4; ++r) {
            float v = psum[mf][r];
            v += __shfl_xor(v, 1); v += __shfl_xor(v, 2);
            v += __shfl_xor(v, 4); v += __shfl_xor(v, 8);
            psum[mf][r] = v + __expf(tauh);
        }

#pragma unroll
    for (int mf = 0; mf < 4; ++mf) {
        const int mq = w * 16 + mf * 128;
#pragma unroll
        for (int r = 0; r < 4; ++r) {
            const long tok = (long)b * 4096 + nb * 512 + mq + hi * 4 + r;
            const float rdn = 1.0f / psum[mf][r];
#pragma unroll
            for (int nfd = 0; nfd < 4; ++nfd)
                o_bf[tok * 2048 + h * 64 + nfd * 16 + r16] = f2b(oacc[mf][nfd][r] * rdn);
        }
    }
}

extern "C" void kernel_launch(void* const* d_in, const int* in_sizes, int n_in,
                              void* d_out, int out_size, void* d_ws, size_t ws_size,
                              hipStream_t stream) {
    const float* hs   = (const float*)d_in[0];
    const float* Wq   = (const float*)d_in[1];
    const float* Wk   = (const float*)d_in[2];
    const float* Wv   = (const float*)d_in[3];
    const float* Wo   = (const float*)d_in[4];
    const float* bias = (const float*)d_in[5];
    const float* tau  = (const float*)d_in[6];
    float* out = (float*)d_out;

    char* p = (char*)d_ws;
    auto alloc = [&](size_t bytes) { char* r = p; p += (bytes + 255) & ~(size_t)255; return r; };
    unsigned short* hs_bf = (unsigned short*)alloc(8192UL * 2048 * 2);
    unsigned short* w1_bf = (unsigned short*)alloc(3072UL * 2048 * 2);
    unsigned short* wo_bf = (unsigned short*)alloc(2048UL * 2048 * 2);
    unsigned short* q_bf  = (unsigned short*)alloc(64UL * 4096 * 64 * 2);
    unsigned short* k_bf  = (unsigned short*)alloc(16UL * 4096 * 64 * 2);
    unsigned short* v_bf  = (unsigned short*)alloc(16UL * 4096 * 64 * 2);
    unsigned short* v_bfT = (unsigned short*)alloc(16UL * 4096 * 64 * 2);
    float2* cs = (float2*)alloc(4096UL * 32 * 8);
    // o_bf aliases hs_bf: hs_bf is dead after gemm128<1>, attn writes o_bf later
    // (stream-ordered). Cuts workspace ~141MB -> ~109MB.
    unsigned short* o_bf = hs_bf;
    if ((size_t)(p - (char*)d_ws) > ws_size) return;  // make failure visible, not corrupting

    cvt_bf16<<<8192, 256, 0, stream>>>(hs, hs_bf, 16777216 / 8);
    cvt_bf16<<<2048, 256, 0, stream>>>(Wq, w1_bf, 4194304 / 8);
    cvt_bf16<<<512, 256, 0, stream>>>(Wk, w1_bf + 2048UL * 2048, 1048576 / 8);
    cvt_bf16<<<512, 256, 0, stream>>>(Wv, w1_bf + 2560UL * 2048, 1048576 / 8);
    cvt_bf16<<<2048, 256, 0, stream>>>(Wo, wo_bf, 4194304 / 8);
    trig_tab<<<512, 256, 0, stream>>>(cs);
    gemm128<1><<<dim3(64, 24), 256, 0, stream>>>(hs_bf, w1_bf, nullptr, q_bf, k_bf, v_bf, cs);
    transpose_v<<<dim3(64, 16), 256, 0, stream>>>(v_bf, v_bfT);
    attn_kernel<<<dim3(8, 32, 2), 512, 0, stream>>>(q_bf, k_bf, v_bfT, bias, tau, o_bf);
    gemm128<0><<<dim3(64, 16), 256, 0, stream>>>(o_bf, wo_bf, out, nullptr, nullptr, nullptr, nullptr);
}

// Round 4
// 528.686 us; speedup vs baseline: 1.0546x; 1.0546x over previous
//
#include <hip/hip_runtime.h>
#include <hip/hip_bf16.h>

typedef __attribute__((ext_vector_type(8))) short short8;
typedef __attribute__((ext_vector_type(4))) float f32x4;

#define DI __device__ __forceinline__

// f32 -> bf16 round-to-nearest-even (bit twiddle; inputs are never NaN)
DI unsigned short f2b(float x) {
    unsigned int u = __builtin_bit_cast(unsigned int, x);
    u += 0x7FFFu + ((u >> 16) & 1u);
    return (unsigned short)(u >> 16);
}

DI void gload_lds16(const void* g, void* l) {
    __builtin_amdgcn_global_load_lds(
        (const __attribute__((address_space(1))) void*)g,
        (__attribute__((address_space(3))) void*)l, 16, 0, 0);
}

// ---------------- f32 -> bf16 bulk convert (vectorized, G13) ----------------
__global__ __launch_bounds__(256) void cvt_bf16(const float* __restrict__ src,
                                                unsigned short* __restrict__ dst, int n8) {
    int i = blockIdx.x * blockDim.x + threadIdx.x;
    if (i >= n8) return;
    const float4* s = (const float4*)src + 2 * (size_t)i;
    float4 a = s[0], b = s[1];
    short8 o;
    o[0] = (short)f2b(a.x); o[1] = (short)f2b(a.y); o[2] = (short)f2b(a.z); o[3] = (short)f2b(a.w);
    o[4] = (short)f2b(b.x); o[5] = (short)f2b(b.y); o[6] = (short)f2b(b.z); o[7] = (short)f2b(b.w);
    *(short8*)(dst + 8 * (size_t)i) = o;
}

// -------- RoPE cos/sin table: [4096 pos][32 freq] float2, f64-accurate -------
__global__ __launch_bounds__(256) void trig_tab(float2* __restrict__ cs) {
    int idx = blockIdx.x * blockDim.x + threadIdx.x;
    if (idx >= 4096 * 32) return;
    int pos = idx >> 5, i = idx & 31;
    double inv = exp(-(double)i * (9.210340371976184 / 32.0)); // 10000^(-i/32)
    double a = (double)pos * inv;
    cs[idx] = make_float2((float)cos(a), (float)sin(a));
}

// ------- 128x128 bf16 GEMM, 2-phase double-buffer + counted vmcnt (T3-min) ---
// Round-3 counters: MfmaUtil 24.6 + VALUBusy 12 -> 63% stall = exposed
// stage->vmcnt(0)->barrier latency. Fix: stage tile t+2 into buf b AFTER this
// iter's reads of buf b retire (lgkmcnt(0)+barrier), MFMA over in-flight loads,
// then vmcnt(4) (= tile t+1's 4 loads landed, tile t+2's still flying) + raw
// s_barrier. Never vmcnt(0) in steady state (T4).
// EPI==0: C (f32, width 2048) = A @ Bw^T   EPI==1: fused QKV + RoPE epilogue
template <int EPI>
__global__ __launch_bounds__(256) void gemm128(const unsigned short* __restrict__ A,
                                               const unsigned short* __restrict__ Bw,
                                               float* __restrict__ Cout,
                                               unsigned short* __restrict__ q_bf,
                                               unsigned short* __restrict__ k_bf,
                                               unsigned short* __restrict__ v_bf,
                                               const float2* __restrict__ cs) {
    constexpr int K = 2048;
    constexpr int NT = K / 32;  // 64 K-tiles
    __shared__ unsigned short At[2][128 * 32];
    __shared__ unsigned short Bt[2][128 * 32];
    const int tid = threadIdx.x;
    const int lane = tid & 63, w = tid >> 6;
    const int wm = w >> 1, wn = w & 1;
    const int bm = blockIdx.x, bn = blockIdx.y;
    const int r16 = lane & 15, hi = lane >> 4;
    const int rowc = tid >> 2, slotc = tid & 3;

    f32x4 acc[4][4] = {};

    auto stage = [&](int t, int b) {
#pragma unroll
        for (int p = 0; p < 2; ++p) {
            int row = p * 64 + rowc;
            gload_lds16(A + (long)(bm * 128 + row) * K + t * 32 + slotc * 8,
                        (char*)At[b] + p * 4096 + w * 1024);
            gload_lds16(Bw + (long)(bn * 128 + row) * K + t * 32 + slotc * 8,
                        (char*)Bt[b] + p * 4096 + w * 1024);
        }
    };

    // prologue: tiles 0,1 in flight; retire tile 0 (oldest 4 of 8), publish.
    stage(0, 0);
    stage(1, 1);
    asm volatile("s_waitcnt vmcnt(4)" ::: "memory");
    __builtin_amdgcn_s_barrier();

    for (int t = 0; t < NT; ++t) {
        const int b = t & 1;
        short8 af[4], bfr[4];
#pragma unroll
        for (int mf = 0; mf < 4; ++mf)
            af[mf] = *(const short8*)(At[b] + (wm * 64 + mf * 16 + r16) * 32 + hi * 8);
#pragma unroll
        for (int nf = 0; nf < 4; ++nf)
            bfr[nf] = *(const short8*)(Bt[b] + (wn * 64 + nf * 16 + r16) * 32 + hi * 8);
        asm volatile("s_waitcnt lgkmcnt(0)" ::: "memory");  // reads of buf b retired
        __builtin_amdgcn_s_barrier();                        // all waves done reading
        const bool more = (t + 2 < NT);
        if (more) stage(t + 2, b);                           // overwrite is now safe
#pragma unroll
        for (int mf = 0; mf < 4; ++mf)
#pragma unroll
            for (int nf = 0; nf < 4; ++nf)
                acc[mf][nf] = __builtin_amdgcn_mfma_f32_16x16x32_bf16(af[mf], bfr[nf], acc[mf][nf], 0, 0, 0);
        if (more) { asm volatile("s_waitcnt vmcnt(4)" ::: "memory"); }  // tile t+1 landed
        else      { asm volatile("s_waitcnt vmcnt(0)" ::: "memory"); }  // tail drain
        __builtin_amdgcn_s_barrier();                        // publish tile t+1
    }

    if (EPI == 0) {
#pragma unroll
        for (int mf = 0; mf < 4; ++mf)
#pragma unroll
            for (int r = 0; r < 4; ++r) {
                long row = (long)bm * 128 + wm * 64 + mf * 16 + hi * 4 + r;
                float* o = Cout + row * 2048 + bn * 128 + wn * 64 + r16;
                o[0] = acc[mf][0][r]; o[16] = acc[mf][1][r]; o[32] = acc[mf][2][r]; o[48] = acc[mf][3][r];
            }
    } else {
        const int colBase = bn * 128 + wn * 64;  // 64-wide span == one head exactly
        const int b = bm >> 5;
        unsigned short* dst;
        bool dorope;
        if (colBase < 2048)      { dst = q_bf + (long)(b * 32 + (colBase >> 6)) * 4096 * 64; dorope = true; }
        else if (colBase < 2560) { dst = k_bf + (long)(b * 8 + ((colBase - 2048) >> 6)) * 4096 * 64; dorope = true; }
        else                     { dst = v_bf + (long)(b * 8 + ((colBase - 2560) >> 6)) * 4096 * 64; dorope = false; }
#pragma unroll
        for (int mf = 0; mf < 4; ++mf)
#pragma unroll
            for (int r = 0; r < 4; ++r) {
                int pos = (bm * 128 + wm * 64 + mf * 16 + hi * 4 + r) & 4095;
                if (dorope) {
#pragma unroll
                    for (int nf = 0; nf < 2; ++nf) {
                        int i = nf * 16 + r16;
                        float2 c2 = cs[pos * 32 + i];
                        float x1 = acc[mf][nf][r], x2 = acc[mf][nf + 2][r];
                        dst[(long)pos * 64 + i]      = f2b(x1 * c2.x - x2 * c2.y);
                        dst[(long)pos * 64 + 32 + i] = f2b(x2 * c2.x + x1 * c2.y);
                    }
                } else {
#pragma unroll
                    for (int nf = 0; nf < 4; ++nf)
                        dst[(long)pos * 64 + nf * 16 + r16] = f2b(acc[mf][nf][r]);
                }
            }
    }
}

// ---------------- V transpose: [plane][pos][d] -> [plane][d][pos] ----------------
__global__ __launch_bounds__(256) void transpose_v(const unsigned short* __restrict__ v,
                                                   unsigned short* __restrict__ vT) {
    __shared__ unsigned short t[64][65];
    const int plane = blockIdx.y;
    const int p0 = blockIdx.x * 64;
    const int tid = threadIdx.x;
    const int rr = tid >> 2, c0 = (tid & 3) * 16;
    const unsigned short* src = v + (long)plane * 4096 * 64 + (long)(p0 + rr) * 64 + c0;
    short8 x0 = *(const short8*)src, x1 = *(const short8*)(src + 8);
#pragma unroll
    for (int j = 0; j < 8; ++j) t[rr][c0 + j] = (unsigned short)x0[j];
#pragma unroll
    for (int j = 0; j < 8; ++j) t[rr][c0 + 8 + j] = (unsigned short)x1[j];
    __syncthreads();
    short8 o0, o1;
#pragma unroll
    for (int j = 0; j < 8; ++j) o0[j] = (short)t[c0 + j][rr];
#pragma unroll
    for (int j = 0; j < 8; ++j) o1[j] = (short)t[c0 + 8 + j][rr];
    unsigned short* d = vT + (long)plane * 64 * 4096 + (long)rr * 4096 + p0 + c0;
    *(short8*)d = o0;
    *(short8*)(d + 8) = o1;
}

// ---------------- sliding-window attention ----------------
// grid (NB=8, H=32, B=2), 512 threads (8 waves). Wave w owns q-rows {w*16 + mf*128}.
// Max-free softmax (logits bounded), normalize by sum + exp(tau) at the end.
// K/V LDS double-buffered with the same counted-vmcnt 2-phase protocol as the
// GEMM (2 loads/thread/tile -> vmcnt(2) steady): stage latency hides under the
// long exp/MFMA compute phase (T14 mechanism). K [kk][d] / V [d][kk], both
// XOR-swizzled via pre-swizzled global source (rule 21). T5 setprio on MFMAs.
__global__ __launch_bounds__(512, 2) void attn_kernel(const unsigned short* __restrict__ q_bf,
                                                      const unsigned short* __restrict__ k_bf,
                                                      const unsigned short* __restrict__ v_bfT,
                                                      const float* __restrict__ bias,
                                                      const float* __restrict__ tau,
                                                      unsigned short* __restrict__ o_bf) {
    __shared__ unsigned short Kt[2][64 * 64];
    __shared__ unsigned short Vt[2][64 * 64];
    __shared__ unsigned short Pl[8][640];  // per-wave [16 q][40] (wave-private)
    __shared__ float bias_l[512];

    const int nb = blockIdx.x, h = blockIdx.y, b = blockIdx.z;
    const int kvh = h >> 2;
    const int tid = threadIdx.x;
    const int lane = tid & 63, w = tid >> 6;
    const int r16 = lane & 15, hi = lane >> 4;

    bias_l[tid] = bias[h * 512 + tid];
    const float tauh = tau[h];

    const unsigned short* qp = q_bf + ((long)(b * 32 + h) * 4096 + nb * 512) * 64;
    const unsigned short* kp = k_bf + (long)(b * 8 + kvh) * 4096 * 64;
    const unsigned short* vp = v_bfT + (long)(b * 8 + kvh) * 64 * 4096;
    const int k0 = nb * 512 - 512;

    short8 aq[4][2];
#pragma unroll
    for (int mf = 0; mf < 4; ++mf) {
        int mq = w * 16 + mf * 128;
#pragma unroll
        for (int dk = 0; dk < 2; ++dk)
            aq[mf][dk] = *(const short8*)(qp + (long)(mq + r16) * 64 + dk * 32 + hi * 8);
    }

    f32x4 oacc[4][4] = {};
    float psum[4][4] = {};

    const int srow = tid >> 3, sslot = tid & 7;
    const int swz = sslot ^ (srow & 7);
    unsigned short* plw = Pl[w];

    auto stageKV = [&](int t, int bb) {
        int jr = k0 + t * 64 + srow; if (jr < 0) jr = 0;
        gload_lds16(kp + (long)jr * 64 + swz * 8, (char*)Kt[bb] + w * 1024);
        int jc = k0 + t * 64 + swz * 8; if (jc < 0) jc = 0;
        gload_lds16(vp + (long)srow * 4096 + jc, (char*)Vt[bb] + w * 1024);
    };

    const int t0 = (nb == 0) ? 8 : 0;  // nb==0: first 8 tiles fully masked
    // prologue: tiles t0,t0+1 in flight; retire tile t0 (2 oldest loads);
    // lgkmcnt(0) publishes bias_l before the barrier.
    stageKV(t0, 0);
    stageKV(t0 + 1, 1);
    asm volatile("s_waitcnt vmcnt(2) lgkmcnt(0)" ::: "memory");
    __builtin_amdgcn_s_barrier();

    for (int t = t0; t < 16; ++t) {
        const int bb = t & 1;  // t0 is even -> consistent with prologue
        short8 bk[4][2], vb[4][2];
#pragma unroll
        for (int nf = 0; nf < 4; ++nf) {
            int rowK = nf * 16 + r16;
            int xo = (rowK & 7) << 4;
#pragma unroll
            for (int ks = 0; ks < 2; ++ks) {
                bk[nf][ks] = *(const short8*)((const char*)Kt[bb] + rowK * 128 + ((hi * 16 + ks * 64) ^ xo));
                vb[nf][ks] = *(const short8*)((const char*)Vt[bb] + rowK * 128 + ((hi * 16 + ks * 64) ^ xo));
            }
        }
        asm volatile("s_waitcnt lgkmcnt(0)" ::: "memory");  // reads of buf bb retired
        __builtin_amdgcn_s_barrier();
        const bool more = (t + 2 < 16);
        if (more) stageKV(t + 2, bb);                        // overwrite safe now

#pragma unroll
        for (int mf = 0; mf < 4; ++mf) {
            const int mq = w * 16 + mf * 128;
            bool valid = (t * 64 + 63 > mq) && (t * 64 <= mq + 527);
            if (!valid) continue;
#pragma unroll
            for (int half = 0; half < 2; ++half) {
#pragma unroll
                for (int nn = 0; nn < 2; ++nn) {
                    const int nfs = half * 2 + nn;
                    f32x4 s = {};
                    __builtin_amdgcn_s_setprio(1);
                    s = __builtin_amdgcn_mfma_f32_16x16x32_bf16(aq[mf][0], bk[nfs][0], s, 0, 0, 0);
                    s = __builtin_amdgcn_mfma_f32_16x16x32_bf16(aq[mf][1], bk[nfs][1], s, 0, 0, 0);
                    __builtin_amdgcn_s_setprio(0);
                    const int kkl = t * 64 + nfs * 16 + r16;
#pragma unroll
                    for (int r = 0; r < 4; ++r) {
                        const int q = mq + hi * 4 + r;
                        const int rel = q - kkl + 512;
                        bool ok = (rel >= 0) && (rel < 512) && (nb > 0 || kkl >= 512);
                        int relc = rel < 0 ? 0 : (rel > 511 ? 511 : rel);
                        float sv = ok ? (s[r] * 0.125f + bias_l[relc]) : -1e30f;
                        float pv = __expf(sv);
                        psum[mf][r] += pv;
                        plw[(hi * 4 + r) * 40 + nn * 16 + r16] = f2b(pv);
                    }
                }
                short8 pa;
                __builtin_memcpy(&pa, plw + r16 * 40 + hi * 8, 16);  // ordered vs the u16 stores
                __builtin_amdgcn_s_setprio(1);
#pragma unroll
                for (int nfd = 0; nfd < 4; ++nfd)
                    oacc[mf][nfd] = __builtin_amdgcn_mfma_f32_16x16x32_bf16(pa, vb[nfd][half], oacc[mf][nfd], 0, 0, 0);
                __builtin_amdgcn_s_setprio(0);
            }
        }
        if (more) { asm volatile("s_waitcnt vmcnt(2)" ::: "memory"); }  // tile t+1 landed
        else      { asm volatile("s_waitcnt vmcnt(0)" ::: "memory"); }
        __builtin_amdgcn_s_barrier();
    }

    // row-sum lives distributed over the 16 lanes sharing `hi`: butterfly over bits 0-3
#pragma unroll
    for (int mf = 0; mf < 4; ++mf)
#pragma unroll
        for (int r = 0; r < 4; ++r) {
            float v = psum[mf][r];
            v += __shfl_xor(v, 1); v += __shfl_xor(v, 2);
            v += __shfl_xor(v, 4); v += __shfl_xor(v, 8);
            psum[mf][r] = v + __expf(tauh);
        }

#pragma unroll
    for (int mf = 0; mf < 4; ++mf) {
        const int mq = w * 16 + mf * 128;
#pragma unroll
        for (int r = 0; r < 4; ++r) {
            const long tok = (long)b * 4096 + nb * 512 + mq + hi * 4 + r;
            const float rdn = 1.0f / psum[mf][r];
#pragma unroll
            for (int nfd = 0; nfd < 4; ++nfd)
                o_bf[tok * 2048 + h * 64 + nfd * 16 + r16] = f2b(oacc[mf][nfd][r] * rdn);
        }
    }
}

extern "C" void kernel_launch(void* const* d_in, const int* in_sizes, int n_in,
                              void* d_out, int out_size, void* d_ws, size_t ws_size,
                              hipStream_t stream) {
    const float* hs   = (const float*)d_in[0];
    const float* Wq   = (const float*)d_in[1];
    const float* Wk   = (const float*)d_in[2];
    const float* Wv   = (const float*)d_in[3];
    const float* Wo   = (const float*)d_in[4];
    const float* bias = (const float*)d_in[5];
    const float* tau  = (const float*)d_in[6];
    float* out = (float*)d_out;

    char* p = (char*)d_ws;
    auto alloc = [&](size_t bytes) { char* r = p; p += (bytes + 255) & ~(size_t)255; return r; };
    unsigned short* hs_bf = (unsigned short*)alloc(8192UL * 2048 * 2);
    unsigned short* w1_bf = (unsigned short*)alloc(3072UL * 2048 * 2);
    unsigned short* wo_bf = (unsigned short*)alloc(2048UL * 2048 * 2);
    unsigned short* q_bf  = (unsigned short*)alloc(64UL * 4096 * 64 * 2);
    unsigned short* k_bf  = (unsigned short*)alloc(16UL * 4096 * 64 * 2);
    unsigned short* v_bf  = (unsigned short*)alloc(16UL * 4096 * 64 * 2);
    unsigned short* v_bfT = (unsigned short*)alloc(16UL * 4096 * 64 * 2);
    float2* cs = (float2*)alloc(4096UL * 32 * 8);
    // o_bf aliases hs_bf: hs_bf is dead after gemm128<1>, attn writes o_bf later
    // (stream-ordered). Cuts workspace ~141MB -> ~109MB.
    unsigned short* o_bf = hs_bf;
    if ((size_t)(p - (char*)d_ws) > ws_size) return;  // make failure visible, not corrupting

    cvt_bf16<<<8192, 256, 0, stream>>>(hs, hs_bf, 16777216 / 8);
    cvt_bf16<<<2048, 256, 0, stream>>>(Wq, w1_bf, 4194304 / 8);
    cvt_bf16<<<512, 256, 0, stream>>>(Wk, w1_bf + 2048UL * 2048, 1048576 / 8);
    cvt_bf16<<<512, 256, 0, stream>>>(Wv, w1_bf + 2560UL * 2048, 1048576 / 8);
    cvt_bf16<<<2048, 256, 0, stream>>>(Wo, wo_bf, 4194304 / 8);
    trig_tab<<<512, 256, 0, stream>>>(cs);
    gemm128<1><<<dim3(64, 24), 256, 0, stream>>>(hs_bf, w1_bf, nullptr, q_bf, k_bf, v_bf, cs);
    transpose_v<<<dim3(64, 16), 256, 0, stream>>>(v_bf, v_bfT);
    attn_kernel<<<dim3(8, 32, 2), 512, 0, stream>>>(q_bf, k_bf, v_bfT, bias, tau, o_bf);
    gemm128<0><<<dim3(64, 16), 256, 0, stream>>>(o_bf, wo_bf, out, nullptr, nullptr, nullptr, nullptr);
}

// Round 7
// 507.089 us; speedup vs baseline: 1.0995x; 1.0426x over previous
//
#include <hip/hip_runtime.h>
#include <hip/hip_bf16.h>

typedef __attribute__((ext_vector_type(8))) short short8;
typedef __attribute__((ext_vector_type(4))) float f32x4;

#define DI __device__ __forceinline__

// f32 -> bf16 round-to-nearest-even (bit twiddle; inputs are never NaN)
DI unsigned short f2b(float x) {
    unsigned int u = __builtin_bit_cast(unsigned int, x);
    u += 0x7FFFu + ((u >> 16) & 1u);
    return (unsigned short)(u >> 16);
}

DI float b2f(unsigned int lo16) {  // low 16 bits = bf16
    unsigned int u = lo16 << 16;
    return __builtin_bit_cast(float, u);
}

DI void gload_lds16(const void* g, void* l) {
    __builtin_amdgcn_global_load_lds(
        (const __attribute__((address_space(1))) void*)g,
        (__attribute__((address_space(3))) void*)l, 16, 0, 0);
}

// ---------------- f32 -> bf16 bulk convert (vectorized, G13) ----------------
__global__ __launch_bounds__(256) void cvt_bf16(const float* __restrict__ src,
                                                unsigned short* __restrict__ dst, int n8) {
    int i = blockIdx.x * blockDim.x + threadIdx.x;
    if (i >= n8) return;
    const float4* s = (const float4*)src + 2 * (size_t)i;
    float4 a = s[0], b = s[1];
    short8 o;
    o[0] = (short)f2b(a.x); o[1] = (short)f2b(a.y); o[2] = (short)f2b(a.z); o[3] = (short)f2b(a.w);
    o[4] = (short)f2b(b.x); o[5] = (short)f2b(b.y); o[6] = (short)f2b(b.z); o[7] = (short)f2b(b.w);
    *(short8*)(dst + 8 * (size_t)i) = o;
}

// -------- RoPE cos/sin table: [4096 pos][32 freq] float2, f64-accurate -------
__global__ __launch_bounds__(256) void trig_tab(float2* __restrict__ cs) {
    int idx = blockIdx.x * blockDim.x + threadIdx.x;
    if (idx >= 4096 * 32) return;
    int pos = idx >> 5, i = idx & 31;
    double inv = exp(-(double)i * (9.210340371976184 / 32.0)); // 10000^(-i/32)
    double a = (double)pos * inv;
    cs[idx] = make_float2((float)cos(a), (float)sin(a));
}

// -------- forward bias table: tab[h][i] = 4 bf16 = bias[h][i-512 .. i-509],
//          zero outside [0,512). In the round-4 lane layout, rel(r) = rel0 + r
//          (consecutive ascending), so one dwordx2 at i = rel0+512 serves all
//          four r's -- replaces 4 LDS b32 gathers on the saturated DS pipe.
__global__ __launch_bounds__(256) void bias_tabf(const float* __restrict__ bias,
                                                 uint2* __restrict__ tab) {
    int idx = blockIdx.x * blockDim.x + threadIdx.x;
    if (idx >= 32 * 1536) return;
    int h = idx / 1536, i = idx - h * 1536;
    unsigned short v[4];
#pragma unroll
    for (int c = 0; c < 4; ++c) {
        int j = i - 512 + c;
        float f = (j >= 0 && j < 512) ? bias[h * 512 + j] : 0.0f;
        v[c] = f2b(f);
    }
    uint2 e;
    e.x = (unsigned)v[0] | ((unsigned)v[1] << 16);
    e.y = (unsigned)v[2] | ((unsigned)v[3] << 16);
    tab[idx] = e;
}

// ------- 128x128 bf16 GEMM, 2-phase double-buffer + counted vmcnt (T3-min) ---
// EPI==0: C (f32, width 2048) = A @ Bw^T   EPI==1: fused QKV + RoPE epilogue
template <int EPI>
__global__ __launch_bounds__(256) void gemm128(const unsigned short* __restrict__ A,
                                               const unsigned short* __restrict__ Bw,
                                               float* __restrict__ Cout,
                                               unsigned short* __restrict__ q_bf,
                                               unsigned short* __restrict__ k_bf,
                                               unsigned short* __restrict__ v_bf,
                                               const float2* __restrict__ cs) {
    constexpr int K = 2048;
    constexpr int NT = K / 32;  // 64 K-tiles
    __shared__ unsigned short At[2][128 * 32];
    __shared__ unsigned short Bt[2][128 * 32];
    const int tid = threadIdx.x;
    const int lane = tid & 63, w = tid >> 6;
    const int wm = w >> 1, wn = w & 1;
    const int bm = blockIdx.x, bn = blockIdx.y;
    const int r16 = lane & 15, hi = lane >> 4;
    const int rowc = tid >> 2, slotc = tid & 3;

    f32x4 acc[4][4] = {};

    auto stage = [&](int t, int b) {
#pragma unroll
        for (int p = 0; p < 2; ++p) {
            int row = p * 64 + rowc;
            gload_lds16(A + (long)(bm * 128 + row) * K + t * 32 + slotc * 8,
                        (char*)At[b] + p * 4096 + w * 1024);
            gload_lds16(Bw + (long)(bn * 128 + row) * K + t * 32 + slotc * 8,
                        (char*)Bt[b] + p * 4096 + w * 1024);
        }
    };

    stage(0, 0);
    stage(1, 1);
    asm volatile("s_waitcnt vmcnt(4)" ::: "memory");
    __builtin_amdgcn_s_barrier();

    for (int t = 0; t < NT; ++t) {
        const int b = t & 1;
        short8 af[4], bfr[4];
#pragma unroll
        for (int mf = 0; mf < 4; ++mf)
            af[mf] = *(const short8*)(At[b] + (wm * 64 + mf * 16 + r16) * 32 + hi * 8);
#pragma unroll
        for (int nf = 0; nf < 4; ++nf)
            bfr[nf] = *(const short8*)(Bt[b] + (wn * 64 + nf * 16 + r16) * 32 + hi * 8);
        asm volatile("s_waitcnt lgkmcnt(0)" ::: "memory");
        __builtin_amdgcn_s_barrier();
        const bool more = (t + 2 < NT);
        if (more) stage(t + 2, b);
#pragma unroll
        for (int mf = 0; mf < 4; ++mf)
#pragma unroll
            for (int nf = 0; nf < 4; ++nf)
                acc[mf][nf] = __builtin_amdgcn_mfma_f32_16x16x32_bf16(af[mf], bfr[nf], acc[mf][nf], 0, 0, 0);
        if (more) { asm volatile("s_waitcnt vmcnt(4)" ::: "memory"); }
        else      { asm volatile("s_waitcnt vmcnt(0)" ::: "memory"); }
        __builtin_amdgcn_s_barrier();
    }

    if (EPI == 0) {
#pragma unroll
        for (int mf = 0; mf < 4; ++mf)
#pragma unroll
            for (int r = 0; r < 4; ++r) {
                long row = (long)bm * 128 + wm * 64 + mf * 16 + hi * 4 + r;
                float* o = Cout + row * 2048 + bn * 128 + wn * 64 + r16;
                o[0] = acc[mf][0][r]; o[16] = acc[mf][1][r]; o[32] = acc[mf][2][r]; o[48] = acc[mf][3][r];
            }
    } else {
        const int colBase = bn * 128 + wn * 64;  // 64-wide span == one head exactly
        const int b = bm >> 5;
        unsigned short* dst;
        bool dorope;
        if (colBase < 2048)      { dst = q_bf + (long)(b * 32 + (colBase >> 6)) * 4096 * 64; dorope = true; }
        else if (colBase < 2560) { dst = k_bf + (long)(b * 8 + ((colBase - 2048) >> 6)) * 4096 * 64; dorope = true; }
        else                     { dst = v_bf + (long)(b * 8 + ((colBase - 2560) >> 6)) * 4096 * 64; dorope = false; }
#pragma unroll
        for (int mf = 0; mf < 4; ++mf)
#pragma unroll
            for (int r = 0; r < 4; ++r) {
                int pos = (bm * 128 + wm * 64 + mf * 16 + hi * 4 + r) & 4095;
                if (dorope) {
#pragma unroll
                    for (int nf = 0; nf < 2; ++nf) {
                        int i = nf * 16 + r16;
                        float2 c2 = cs[pos * 32 + i];
                        float x1 = acc[mf][nf][r], x2 = acc[mf][nf + 2][r];
                        dst[(long)pos * 64 + i]      = f2b(x1 * c2.x - x2 * c2.y);
                        dst[(long)pos * 64 + 32 + i] = f2b(x2 * c2.x + x1 * c2.y);
                    }
                } else {
#pragma unroll
                    for (int nf = 0; nf < 4; ++nf)
                        dst[(long)pos * 64 + nf * 16 + r16] = f2b(acc[mf][nf][r]);
                }
            }
    }
}

// ---------------- V transpose: [plane][pos][d] -> [plane][d][pos] ----------------
__global__ __launch_bounds__(256) void transpose_v(const unsigned short* __restrict__ v,
                                                   unsigned short* __restrict__ vT) {
    __shared__ unsigned short t[64][65];
    const int plane = blockIdx.y;
    const int p0 = blockIdx.x * 64;
    const int tid = threadIdx.x;
    const int rr = tid >> 2, c0 = (tid & 3) * 16;
    const unsigned short* src = v + (long)plane * 4096 * 64 + (long)(p0 + rr) * 64 + c0;
    short8 x0 = *(const short8*)src, x1 = *(const short8*)(src + 8);
#pragma unroll
    for (int j = 0; j < 8; ++j) t[rr][c0 + j] = (unsigned short)x0[j];
#pragma unroll
    for (int j = 0; j < 8; ++j) t[rr][c0 + 8 + j] = (unsigned short)x1[j];
    __syncthreads();
    short8 o0, o1;
#pragma unroll
    for (int j = 0; j < 8; ++j) o0[j] = (short)t[c0 + j][rr];
#pragma unroll
    for (int j = 0; j < 8; ++j) o1[j] = (short)t[c0 + 8 + j][rr];
    unsigned short* d = vT + (long)plane * 64 * 4096 + (long)rr * 4096 + p0 + c0;
    *(short8*)d = o0;
    *(short8*)(d + 8) = o1;
}

// ---------------- sliding-window attention (round-4 structure + bias table) --
// grid (NB=8, H=32, B=2), 512 threads (8 waves). Wave w owns q-rows {w*16+mf*128}.
// Max-free softmax (logits bounded): accumulate exp(s), normalize by sum+exp(tau).
// K/V double-buffered, counted-vmcnt 2-phase protocol. P routed through wave-
// private LDS (validated round 3/4). ONLY change vs round 4: bias comes from the
// forward-packed global bf16-quad table (1 dwordx2 per 16x16 slot) instead of 16
// LDS b32 gathers -- the DS pipe was ~85-90% saturated (round-4 PMC).
__global__ __launch_bounds__(512, 2) void attn_kernel(const unsigned short* __restrict__ q_bf,
                                                      const unsigned short* __restrict__ k_bf,
                                                      const unsigned short* __restrict__ v_bfT,
                                                      const uint2* __restrict__ tab,
                                                      const float* __restrict__ tau,
                                                      unsigned short* __restrict__ o_bf) {
    __shared__ unsigned short Kt[2][64 * 64];
    __shared__ unsigned short Vt[2][64 * 64];
    __shared__ unsigned short Pl[8][640];  // per-wave [16 q][40] (wave-private)

    const int nb = blockIdx.x, h = blockIdx.y, b = blockIdx.z;
    const int kvh = h >> 2;
    const int tid = threadIdx.x;
    const int lane = tid & 63, w = tid >> 6;
    const int r16 = lane & 15, hi = lane >> 4;

    const float tauh = tau[h];
    const uint2* tabh = tab + h * 1536;

    const unsigned short* qp = q_bf + ((long)(b * 32 + h) * 4096 + nb * 512) * 64;
    const unsigned short* kp = k_bf + (long)(b * 8 + kvh) * 4096 * 64;
    const unsigned short* vp = v_bfT + (long)(b * 8 + kvh) * 64 * 4096;
    const int k0 = nb * 512 - 512;

    short8 aq[4][2];
#pragma unroll
    for (int mf = 0; mf < 4; ++mf) {
        int mq = w * 16 + mf * 128;
#pragma unroll
        for (int dk = 0; dk < 2; ++dk)
            aq[mf][dk] = *(const short8*)(qp + (long)(mq + r16) * 64 + dk * 32 + hi * 8);
    }

    f32x4 oacc[4][4] = {};
    float psum[4][4] = {};

    const int srow = tid >> 3, sslot = tid & 7;
    const int swz = sslot ^ (srow & 7);
    unsigned short* plw = Pl[w];

    auto stageKV = [&](int t, int bb) {
        int jr = k0 + t * 64 + srow; if (jr < 0) jr = 0;
        gload_lds16(kp + (long)jr * 64 + swz * 8, (char*)Kt[bb] + w * 1024);
        int jc = k0 + t * 64 + swz * 8; if (jc < 0) jc = 0;
        gload_lds16(vp + (long)srow * 4096 + jc, (char*)Vt[bb] + w * 1024);
    };

    const int t0 = (nb == 0) ? 8 : 0;  // nb==0: first 8 tiles fully masked
    stageKV(t0, 0);
    stageKV(t0 + 1, 1);
    asm volatile("s_waitcnt vmcnt(2)" ::: "memory");
    __builtin_amdgcn_s_barrier();

    for (int t = t0; t < 16; ++t) {
        const int bb = t & 1;  // t0 even -> consistent with prologue
        short8 bk[4][2], vb[4][2];
#pragma unroll
        for (int nf = 0; nf < 4; ++nf) {
            int rowK = nf * 16 + r16;
            int xo = (rowK & 7) << 4;
#pragma unroll
            for (int ks = 0; ks < 2; ++ks) {
                bk[nf][ks] = *(const short8*)((const char*)Kt[bb] + rowK * 128 + ((hi * 16 + ks * 64) ^ xo));
                vb[nf][ks] = *(const short8*)((const char*)Vt[bb] + rowK * 128 + ((hi * 16 + ks * 64) ^ xo));
            }
        }
        asm volatile("s_waitcnt lgkmcnt(0)" ::: "memory");  // reads of buf bb retired
        __builtin_amdgcn_s_barrier();
        const bool more = (t + 2 < 16);
        if (more) stageKV(t + 2, bb);

#pragma unroll
        for (int mf = 0; mf < 4; ++mf) {
            const int mq = w * 16 + mf * 128;
            bool valid = (t * 64 + 63 > mq) && (t * 64 <= mq + 527);
            if (!valid) continue;
#pragma unroll
            for (int half = 0; half < 2; ++half) {
#pragma unroll
                for (int nn = 0; nn < 2; ++nn) {
                    const int nfs = half * 2 + nn;
                    f32x4 s = {};
                    __builtin_amdgcn_s_setprio(1);
                    s = __builtin_amdgcn_mfma_f32_16x16x32_bf16(aq[mf][0], bk[nfs][0], s, 0, 0, 0);
                    s = __builtin_amdgcn_mfma_f32_16x16x32_bf16(aq[mf][1], bk[nfs][1], s, 0, 0, 0);
                    __builtin_amdgcn_s_setprio(0);
                    const int kkl = t * 64 + nfs * 16 + r16;
                    // rel(r) = rel0 + r, consecutive -> one bf16-quad table load
                    const int rel0 = mq + hi * 4 - kkl + 512;
                    uint2 e = tabh[rel0 + 512];
#pragma unroll
                    for (int r = 0; r < 4; ++r) {
                        const int rel = rel0 + r;
                        bool ok = (rel >= 0) && (rel < 512) && (nb > 0 || kkl >= 512);
                        unsigned int hv = (r & 2) ? e.y : e.x;
                        float bv = b2f((r & 1) ? (hv >> 16) : (hv & 0xFFFFu));
                        float sv = ok ? (s[r] * 0.125f + bv) : -1e30f;
                        float pv = __expf(sv);
                        psum[mf][r] += pv;
                        plw[(hi * 4 + r) * 40 + nn * 16 + r16] = f2b(pv);
                    }
                }
                short8 pa;
                __builtin_memcpy(&pa, plw + r16 * 40 + hi * 8, 16);  // ordered vs the u16 stores
                __builtin_amdgcn_s_setprio(1);
#pragma unroll
                for (int nfd = 0; nfd < 4; ++nfd)
                    oacc[mf][nfd] = __builtin_amdgcn_mfma_f32_16x16x32_bf16(pa, vb[nfd][half], oacc[mf][nfd], 0, 0, 0);
                __builtin_amdgcn_s_setprio(0);
            }
        }
        if (more) { asm volatile("s_waitcnt vmcnt(2)" ::: "memory"); }
        else      { asm volatile("s_waitcnt vmcnt(0)" ::: "memory"); }
        __builtin_amdgcn_s_barrier();
    }

    // row-sum lives distributed over the 16 lanes sharing `hi`: butterfly over bits 0-3
#pragma unroll
    for (int mf = 0; mf < 4; ++mf)
#pragma unroll
        for (int r = 0; r < 4; ++r) {
            float v = psum[mf][r];
            v += __shfl_xor(v, 1); v += __shfl_xor(v, 2);
            v += __shfl_xor(v, 4); v += __shfl_xor(v, 8);
            psum[mf][r] = v + __expf(tauh);
        }

#pragma unroll
    for (int mf = 0; mf < 4; ++mf) {
        const int mq = w * 16 + mf * 128;
#pragma unroll
        for (int r = 0; r < 4; ++r) {
            const long tok = (long)b * 4096 + nb * 512 + mq + hi * 4 + r;
            const float rdn = 1.0f / psum[mf][r];
#pragma unroll
            for (int nfd = 0; nfd < 4; ++nfd)
                o_bf[tok * 2048 + h * 64 + nfd * 16 + r16] = f2b(oacc[mf][nfd][r] * rdn);
        }
    }
}

extern "C" void kernel_launch(void* const* d_in, const int* in_sizes, int n_in,
                              void* d_out, int out_size, void* d_ws, size_t ws_size,
                              hipStream_t stream) {
    const float* hs   = (const float*)d_in[0];
    const float* Wq   = (const float*)d_in[1];
    const float* Wk   = (const float*)d_in[2];
    const float* Wv   = (const float*)d_in[3];
    const float* Wo   = (const float*)d_in[4];
    const float* bias = (const float*)d_in[5];
    const float* tau  = (const float*)d_in[6];
    float* out = (float*)d_out;

    char* p = (char*)d_ws;
    auto alloc = [&](size_t bytes) { char* r = p; p += (bytes + 255) & ~(size_t)255; return r; };
    unsigned short* hs_bf = (unsigned short*)alloc(8192UL * 2048 * 2);
    unsigned short* w1_bf = (unsigned short*)alloc(3072UL * 2048 * 2);
    unsigned short* wo_bf = (unsigned short*)alloc(2048UL * 2048 * 2);
    unsigned short* q_bf  = (unsigned short*)alloc(64UL * 4096 * 64 * 2);
    unsigned short* k_bf  = (unsigned short*)alloc(16UL * 4096 * 64 * 2);
    unsigned short* v_bf  = (unsigned short*)alloc(16UL * 4096 * 64 * 2);
    unsigned short* v_bfT = (unsigned short*)alloc(16UL * 4096 * 64 * 2);
    float2* cs = (float2*)alloc(4096UL * 32 * 8);
    uint2* tab = (uint2*)alloc(32UL * 1536 * 8);
    // o_bf aliases hs_bf: hs_bf is dead after gemm128<1>, attn writes o_bf later.
    unsigned short* o_bf = hs_bf;
    if ((size_t)(p - (char*)d_ws) > ws_size) return;

    cvt_bf16<<<8192, 256, 0, stream>>>(hs, hs_bf, 16777216 / 8);
    cvt_bf16<<<2048, 256, 0, stream>>>(Wq, w1_bf, 4194304 / 8);
    cvt_bf16<<<512, 256, 0, stream>>>(Wk, w1_bf + 2048UL * 2048, 1048576 / 8);
    cvt_bf16<<<512, 256, 0, stream>>>(Wv, w1_bf + 2560UL * 2048, 1048576 / 8);
    cvt_bf16<<<2048, 256, 0, stream>>>(Wo, wo_bf, 4194304 / 8);
    trig_tab<<<512, 256, 0, stream>>>(cs);
    bias_tabf<<<192, 256, 0, stream>>>(bias, tab);
    gemm128<1><<<dim3(64, 24), 256, 0, stream>>>(hs_bf, w1_bf, nullptr, q_bf, k_bf, v_bf, cs);
    transpose_v<<<dim3(64, 16), 256, 0, stream>>>(v_bf, v_bfT);
    attn_kernel<<<dim3(8, 32, 2), 512, 0, stream>>>(q_bf, k_bf, v_bfT, tab, tau, o_bf);
    gemm128<0><<<dim3(64, 16), 256, 0, stream>>>(o_bf, wo_bf, out, nullptr, nullptr, nullptr, nullptr);
}